// Round 17
// baseline (750.315 us; speedup 1.0000x reference)
//
#include <hip/hip_runtime.h>
#include <stdint.h>

// BitNet b1.58 column-parallel linear:
//   y[m,n] = (sum_k qx[m,k]*qw[n,k]) * inv_sx[m] * inv_sw + bias[n]
// M=8192 (B*S), N=16384 (D_OUT), K=4096 (D_IN)
//
// HYBRID GEMM: A fragments via LDS (R9 machinery, 85 B/cy pipe), B fragments via
// pre-packed global->register loads (R16 machinery, L2/L1 pipe). Splitting the
// fragment traffic puts every resource below the MFMA pipe time (1306 cy/pair-step):
// LDS ~1000 cy, L2 ~1143 cy. Both sides byte-verified in earlier rounds.

#define M_ROWS 8192
#define N_COLS 16384
#define K_DIM  4096
#define NT     (K_DIM / 64)   // 64 K-steps of 64 bytes

typedef int v4i __attribute__((ext_vector_type(4)));

// ---------------- workspace layout ----------------
#define WS_PARTIALS 0
#define WS_PARAMS   8192
#define WS_INVSX    8448
#define WS_QX       41216
#define WS_QW       (41216 + 33554432)
#define WS_NEED     ((size_t)WS_QW + 67108864)

#define QP 1028   // padded ints per row in the w-pack LDS transpose tile

__device__ __forceinline__ int quant_act1(float v, float s) {
    float q = rintf(v * s);               // round-half-even, matches jnp.round
    q = fminf(127.0f, fmaxf(-128.0f, q));
    return (int)q;
}
__device__ __forceinline__ int quant_w1(float v, float s) {
    float q = rintf(v * s);
    q = fminf(1.0f, fmaxf(-1.0f, q));
    return (int)q;
}

// ---------------- fused: act quant row-major (blocks 0..8191) + weight abs-sum
// partials (blocks 8192..10239) ----------------
__global__ __launch_bounds__(256) void fused_quant_kernel(const float* __restrict__ x,
                                                          int8_t* __restrict__ qx,
                                                          float* __restrict__ inv_sx,
                                                          const float* __restrict__ w,
                                                          float* __restrict__ partials) {
    const int t = threadIdx.x;
    if (blockIdx.x < 8192) {
        const int row = blockIdx.x;
        const float4* xr = (const float4*)(x + (size_t)row * K_DIM);

        float4 v[4];
        float m = 0.0f;
#pragma unroll
        for (int i = 0; i < 4; ++i) {
            v[i] = xr[t + 256 * i];
            m = fmaxf(m, fmaxf(fmaxf(fabsf(v[i].x), fabsf(v[i].y)),
                               fmaxf(fabsf(v[i].z), fabsf(v[i].w))));
        }
#pragma unroll
        for (int off = 32; off > 0; off >>= 1) m = fmaxf(m, __shfl_xor(m, off));
        __shared__ float wm[4];
        if ((t & 63) == 0) wm[t >> 6] = m;
        __syncthreads();
        m = fmaxf(fmaxf(wm[0], wm[1]), fmaxf(wm[2], wm[3]));
        m = fmaxf(m, 1e-5f);              // clip(max, EPS)
        const float scale = 127.0f / m;
        if (t == 0) inv_sx[row] = 1.0f / scale;

        int* qr = (int*)(qx + (size_t)row * K_DIM);
#pragma unroll
        for (int i = 0; i < 4; ++i) {
            int b0 = quant_act1(v[i].x, scale) & 255;
            int b1 = quant_act1(v[i].y, scale) & 255;
            int b2 = quant_act1(v[i].z, scale) & 255;
            int b3 = quant_act1(v[i].w, scale) & 255;
            qr[t + 256 * i] = b0 | (b1 << 8) | (b2 << 16) | (b3 << 24);
        }
    } else {
        const int pb = blockIdx.x - 8192;             // 0..2047
        const size_t base = (size_t)pb * 8192;        // float4 units
        const float4* w4 = (const float4*)w;
        float s = 0.0f;
#pragma unroll 8
        for (int i = 0; i < 32; ++i) {
            float4 v = w4[base + (size_t)i * 256 + t];
            s += fabsf(v.x) + fabsf(v.y) + fabsf(v.z) + fabsf(v.w);
        }
#pragma unroll
        for (int off = 32; off > 0; off >>= 1) s += __shfl_xor(s, off);
        __shared__ float wp[4];
        if ((t & 63) == 0) wp[t >> 6] = s;
        __syncthreads();
        if (t == 0) partials[pb] = (wp[0] + wp[1]) + (wp[2] + wp[3]);
    }
}

__global__ __launch_bounds__(256) void wfinal_kernel(const float* __restrict__ partials,
                                                     float* __restrict__ params) {
    __shared__ double sh[256];
    const int t = threadIdx.x;
    double s = 0.0;
    for (int i = t; i < 2048; i += 256) s += (double)partials[i];
    sh[t] = s;
    __syncthreads();
    for (int off = 128; off > 0; off >>= 1) {
        if (t < off) sh[t] += sh[t + off];
        __syncthreads();
    }
    if (t == 0) {
        float mean = (float)(sh[0] / 67108864.0);
        mean = fmaxf(mean, 1e-5f);        // clip(mean, EPS)
        float scale = 1.0f / mean;        // scale_w
        params[0] = scale;
        params[1] = 1.0f / scale;         // inv_sw
    }
}

// ---------------- weight quant + pack (R16-verified): packed[rowblk][kstep][lane] ----
// lane l <-> (row = rowblk*16 + (l&15), kbytes = kstep*64 + (l>>4)*16 .. +16)
__global__ __launch_bounds__(256) void w_quant_pack_kernel(const float* __restrict__ w,
                                                           int8_t* __restrict__ qwp,
                                                           const float* __restrict__ params) {
    __shared__ int qtile[16 * QP];
    const int t = threadIdx.x;
    const int wv = t >> 6, lane = t & 63;
    const int rowbase = blockIdx.x * 16;
    const float s = params[0];

#pragma unroll 1
    for (int r = 0; r < 16; ++r) {
        const float4* wr4 = (const float4*)(w + (size_t)(rowbase + r) * K_DIM);
#pragma unroll
        for (int i = 0; i < 4; ++i) {
            float4 v = wr4[t + 256 * i];
            int b0 = quant_w1(v.x, s) & 255;
            int b1 = quant_w1(v.y, s) & 255;
            int b2 = quant_w1(v.z, s) & 255;
            int b3 = quant_w1(v.w, s) & 255;
            qtile[r * QP + t + 256 * i] = b0 | (b1 << 8) | (b2 << 16) | (b3 << 24);
        }
    }
    __syncthreads();

    int8_t* out = qwp + (size_t)blockIdx.x * 65536;
    const int rr = lane & 15, sub = lane >> 4;
#pragma unroll 1
    for (int ks = 0; ks < 16; ++ks) {
        const int kstep = wv * 16 + ks;
        v4i c = *(const v4i*)&qtile[rr * QP + kstep * 16 + sub * 4];
        *(v4i*)(out + (size_t)kstep * 1024 + lane * 16) = c;
    }
}

// ---------------- int8 GEMM: HYBRID — A via LDS ring-3, B via packed global->regs ----
// 256x128 tile, 4 waves (2M x 2N), per-wave 128x64, mfma_i32_16x16x64_i8, 2 blocks/CU
// (LDS 48KB/block). Per step t (slot s=t%3):
//   { 8 ds_read A-frags(slot s) | BL(t+1)->other B-reg set (4 coalesced dwordx4) |
//     AG(t+2 -> (t+2)%3) (4 global_load_lds) | 32 MFMA | vmcnt(8) | s_barrier }
// vmcnt(8): this step issued 8 VMEM ops; everything older (incl. AG(t+1)) proven;
// barrier publishes slot (t+1)%3. B-reg consumption is a compiler-visible register
// dep -> hipcc inserts its own counted vmcnt before first MFMA use. Slot-overwrite
// distance = R9's argument (readers drained before the end-of-(t-1) barrier).
// A swizzle/aoff/epilogue = R9 verbatim; B packed map = R16 verbatim (both exact-int
// verified; any violation would explode absmax).
__global__ __launch_bounds__(256, 2) void gemm_i8_kernel(const int8_t* __restrict__ qx,
                                                         const int8_t* __restrict__ qwp,
                                                         const float* __restrict__ inv_sx,
                                                         const float* __restrict__ params,
                                                         const float* __restrict__ bias,
                                                         float* __restrict__ y) {
    __shared__ __align__(16) int8_t lds[3][16384];   // A[256][64] per slot
    int8_t* L = &lds[0][0];

    const int tid = threadIdx.x;
    const int lane = tid & 63;
    const int w = tid >> 6;           // wave 0..3
    const int wr = w >> 1;            // 0..1  (M half)
    const int wc = w & 1;             // 0..1  (N half)

    // XCD-aware bijective swizzle: 4096 blocks, 8 XCDs; bn-fast (A panel L2-resident)
    const int bid = blockIdx.x;
    const int swz = (bid & 7) * 512 + (bid >> 3);
    const int bn = swz & 127;         // 128 n-blocks
    const int bm = swz >> 7;          // 32 m-blocks

    const int arow0 = bm * 256;
    const int bcol0 = bn * 128;

    // A staging: 4 chunks/thread (rows r0+{0,64,128,192}), swizzled source (R9)
    const int r0 = tid >> 2;
    const int kc0 = (tid & 3) ^ ((r0 >> 1) & 3);
    const int8_t* gA = qx + ((size_t)arow0 + r0) * K_DIM + kc0 * 16;

    // B fragment base (packed, R16): rowblk stride 65536, kstep stride 1024, lane*16
    const int8_t* pB = qwp + (size_t)((bcol0 >> 4) + wc * 4) * 65536 + lane * 16;

#define GLD(g, l)                                                                        \
    __builtin_amdgcn_global_load_lds((const __attribute__((address_space(1))) void*)(g), \
                                     (__attribute__((address_space(3))) void*)(l), 16, 0, 0)

#define AG(ks, S)                                                                        \
    do {                                                                                 \
        const size_t _o = (size_t)(ks) * 64;                                             \
        _Pragma("unroll") for (int _g = 0; _g < 4; ++_g)                                 \
            GLD(gA + _o + (size_t)_g * (64 * K_DIM),                                     \
                L + (S) * 16384 + _g * 4096 + tid * 16);                                 \
    } while (0)

#define BL(DST, t)                                                                       \
    do {                                                                                 \
        _Pragma("unroll") for (int _j = 0; _j < 4; ++_j)                                 \
            DST[_j] = *(const v4i*)(pB + (size_t)_j * 65536 + (size_t)(t) * 1024);       \
    } while (0)

    // A fragment ds_read offsets (R9-verified, 0 conflicts)
    const int ksub = lane >> 4;
    const int lrow = lane & 15;
    int aoff[8];
#pragma unroll
    for (int i = 0; i < 8; ++i) {
        int ra = wr * 128 + i * 16 + lrow;
        aoff[i] = ra * 64 + ((ksub ^ ((ra >> 1) & 3)) << 4);
    }

    v4i acc[8][4];
#pragma unroll
    for (int i = 0; i < 8; ++i)
#pragma unroll
        for (int j = 0; j < 4; ++j) acc[i][j] = (v4i){0, 0, 0, 0};

    v4i bE[4], bO[4];

#define BARR()                                                                 \
    do {                                                                       \
        __builtin_amdgcn_s_barrier();                                          \
        __builtin_amdgcn_sched_barrier(0);                                     \
    } while (0)
#define VM(NSTR) asm volatile("s_waitcnt vmcnt(" NSTR ")" ::: "memory")

// One K-step: 8 A ds_reads from slot CS, BL(TB)->BN, AG(TA->SA), 32 MFMA with BC,
// counted vmcnt, barrier.
#define STEP(CS, BC, BN, TB, TA, SA, DO_BL, DO_AG, VMSTMT, DOBAR)              \
    do {                                                                       \
        const int8_t* _p = L + (CS) * 16384;                                   \
        v4i a[8];                                                              \
        _Pragma("unroll") for (int _i = 0; _i < 8; ++_i)                       \
            a[_i] = *(const v4i*)(_p + aoff[_i]);                              \
        if (DO_BL) BL(BN, TB);                                                 \
        if (DO_AG) AG(TA, SA);                                                 \
        __builtin_amdgcn_s_setprio(1);                                         \
        _Pragma("unroll") for (int _i = 0; _i < 8; ++_i)                       \
            _Pragma("unroll") for (int _j = 0; _j < 4; ++_j)                   \
                acc[_i][_j] = __builtin_amdgcn_mfma_i32_16x16x64_i8(           \
                    a[_i], BC[_j], acc[_i][_j], 0, 0, 0);                      \
        __builtin_amdgcn_s_setprio(0);                                         \
        VMSTMT;                                                                \
        if (DOBAR) BARR();                                                     \
    } while (0)

    // prologue: B(0)->bE; stage A0->s0, A1->s1; vmcnt(4) proves BL0+AG0; publish s0
    BL(bE, 0);
    AG(0, 0);
    AG(1, 1);
    VM("4");
    BARR();

    // main loop: 10 iters x 6 steps (t=0..59); slot=t%3, B parity E(even)/O(odd)
#pragma unroll 1
    for (int j = 0; j < 10; ++j) {
        const int tb = 6 * j;
        STEP(0, bE, bO, tb + 1, tb + 2, 2, 1, 1, VM("8"), 1);
        STEP(1, bO, bE, tb + 2, tb + 3, 0, 1, 1, VM("8"), 1);
        STEP(2, bE, bO, tb + 3, tb + 4, 1, 1, 1, VM("8"), 1);
        STEP(0, bO, bE, tb + 4, tb + 5, 2, 1, 1, VM("8"), 1);
        STEP(1, bE, bO, tb + 5, tb + 6, 0, 1, 1, VM("8"), 1);
        STEP(2, bO, bE, tb + 6, tb + 7, 1, 1, 1, VM("8"), 1);
    }
    // tail: t=60..63
    STEP(0, bE, bO, 61, 62, 2, 1, 1, VM("8"), 1);   // t=60: proves AG(61)
    STEP(1, bO, bE, 62, 63, 0, 1, 1, VM("8"), 1);   // t=61: proves AG(62)
    STEP(2, bE, bO, 63, 0, 0, 1, 0, VM("4"), 1);    // t=62: proves AG(63)
    STEP(0, bO, bE, 0, 0, 0, 0, 0, (void)0, 0);     // t=63 (B(63) compiler-proven)

    // epilogue: y = acc * inv_sx[row] * inv_sw + bias[col]  (verified 16x16 C/D layout)
    const float invsw = params[1];
    const int rl = (lane >> 4) * 4;
#pragma unroll
    for (int i = 0; i < 8; ++i) {
        const int grow_base = arow0 + wr * 128 + i * 16 + rl;
        float isx[4];
#pragma unroll
        for (int r = 0; r < 4; ++r) isx[r] = inv_sx[grow_base + r] * invsw;
#pragma unroll
        for (int j = 0; j < 4; ++j) {
            const int gcol = bcol0 + wc * 64 + j * 16 + lrow;
            const float bb = bias[gcol];
#pragma unroll
            for (int r = 0; r < 4; ++r) {
                y[(size_t)(grow_base + r) * N_COLS + gcol] =
                    (float)acc[i][j][r] * isx[r] + bb;
            }
        }
    }
#undef GLD
#undef AG
#undef BL
#undef BARR
#undef VM
#undef STEP
}

// ---------------- launch ----------------
extern "C" void kernel_launch(void* const* d_in, const int* in_sizes, int n_in,
                              void* d_out, int out_size, void* d_ws, size_t ws_size,
                              hipStream_t stream) {
    const float* x    = (const float*)d_in[0];
    const float* wt   = (const float*)d_in[1];
    const float* bias = (const float*)d_in[2];
    float* y = (float*)d_out;

    if (ws_size < WS_NEED) return;

    char* ws = (char*)d_ws;
    float* partials = (float*)(ws + WS_PARTIALS);
    float* params   = (float*)(ws + WS_PARAMS);
    float* inv_sx   = (float*)(ws + WS_INVSX);
    int8_t* qx  = (int8_t*)(ws + WS_QX);    // row-major (A side)
    int8_t* qwp = (int8_t*)(ws + WS_QW);    // packed fragments (B side)

    hipLaunchKernelGGL(fused_quant_kernel, dim3(10240), dim3(256), 0, stream,
                       x, qx, inv_sx, wt, partials);
    hipLaunchKernelGGL(wfinal_kernel,      dim3(1),    dim3(256), 0, stream, partials, params);
    hipLaunchKernelGGL(w_quant_pack_kernel,dim3(1024), dim3(256), 0, stream, wt, qwp, params);
    hipLaunchKernelGGL(gemm_i8_kernel,     dim3(4096), dim3(256), 0, stream,
                       qx, qwp, inv_sx, params, bias, y);
}

// Round 18
// 715.424 us; speedup vs baseline: 1.0488x; 1.0488x over previous
//
#include <hip/hip_runtime.h>
#include <stdint.h>

// BitNet b1.58 column-parallel linear:
//   y[m,n] = (sum_k qx[m,k]*qw[n,k]) * inv_sx[m] * inv_sw + bias[n]
// M=8192 (B*S), N=16384 (D_OUT), K=4096 (D_IN)
//
// Byte-faithful i8 port of the m201 256x256 8-phase template (the config measured at
// 62% MfmaUtil for bf16 on this chip): BK=128B, 8 waves/512thr, 2x64KB LDS dbuf,
// 4 phases per K-tile with 16-MFMA clusters, 1 half-tile staged per phase,
// counted vmcnt(6) twice per tile (never 0 until the tail).

#define M_ROWS 8192
#define N_COLS 16384
#define K_DIM  4096
#define NT2    32            // K-tiles of 128 bytes

typedef int v4i __attribute__((ext_vector_type(4)));

// ---------------- workspace layout ----------------
#define WS_PARTIALS 0
#define WS_PARAMS   8192
#define WS_INVSX    8448
#define WS_QX       41216
#define WS_QW       (41216 + 33554432)
#define WS_NEED     ((size_t)WS_QW + 67108864)

__device__ __forceinline__ int quant_act1(float v, float s) {
    float q = rintf(v * s);               // round-half-even, matches jnp.round
    q = fminf(127.0f, fmaxf(-128.0f, q));
    return (int)q;
}
__device__ __forceinline__ int quant_w1(float v, float s) {
    float q = rintf(v * s);
    q = fminf(1.0f, fmaxf(-1.0f, q));
    return (int)q;
}

// ---------------- fused: act quant (blocks 0..8191) + weight abs-sum partials ----------
__global__ __launch_bounds__(256) void fused_quant_kernel(const float* __restrict__ x,
                                                          int8_t* __restrict__ qx,
                                                          float* __restrict__ inv_sx,
                                                          const float* __restrict__ w,
                                                          float* __restrict__ partials) {
    const int t = threadIdx.x;
    if (blockIdx.x < 8192) {
        const int row = blockIdx.x;
        const float4* xr = (const float4*)(x + (size_t)row * K_DIM);

        float4 v[4];
        float m = 0.0f;
#pragma unroll
        for (int i = 0; i < 4; ++i) {
            v[i] = xr[t + 256 * i];
            m = fmaxf(m, fmaxf(fmaxf(fabsf(v[i].x), fabsf(v[i].y)),
                               fmaxf(fabsf(v[i].z), fabsf(v[i].w))));
        }
#pragma unroll
        for (int off = 32; off > 0; off >>= 1) m = fmaxf(m, __shfl_xor(m, off));
        __shared__ float wm[4];
        if ((t & 63) == 0) wm[t >> 6] = m;
        __syncthreads();
        m = fmaxf(fmaxf(wm[0], wm[1]), fmaxf(wm[2], wm[3]));
        m = fmaxf(m, 1e-5f);              // clip(max, EPS)
        const float scale = 127.0f / m;
        if (t == 0) inv_sx[row] = 1.0f / scale;

        int* qr = (int*)(qx + (size_t)row * K_DIM);
#pragma unroll
        for (int i = 0; i < 4; ++i) {
            int b0 = quant_act1(v[i].x, scale) & 255;
            int b1 = quant_act1(v[i].y, scale) & 255;
            int b2 = quant_act1(v[i].z, scale) & 255;
            int b3 = quant_act1(v[i].w, scale) & 255;
            qr[t + 256 * i] = b0 | (b1 << 8) | (b2 << 16) | (b3 << 24);
        }
    } else {
        const int pb = blockIdx.x - 8192;             // 0..2047
        const size_t base = (size_t)pb * 8192;        // float4 units
        const float4* w4 = (const float4*)w;
        float s = 0.0f;
#pragma unroll 8
        for (int i = 0; i < 32; ++i) {
            float4 v = w4[base + (size_t)i * 256 + t];
            s += fabsf(v.x) + fabsf(v.y) + fabsf(v.z) + fabsf(v.w);
        }
#pragma unroll
        for (int off = 32; off > 0; off >>= 1) s += __shfl_xor(s, off);
        __shared__ float wp[4];
        if ((t & 63) == 0) wp[t >> 6] = s;
        __syncthreads();
        if (t == 0) partials[pb] = (wp[0] + wp[1]) + (wp[2] + wp[3]);
    }
}

__global__ __launch_bounds__(256) void wfinal_kernel(const float* __restrict__ partials,
                                                     float* __restrict__ params) {
    __shared__ double sh[256];
    const int t = threadIdx.x;
    double s = 0.0;
    for (int i = t; i < 2048; i += 256) s += (double)partials[i];
    sh[t] = s;
    __syncthreads();
    for (int off = 128; off > 0; off >>= 1) {
        if (t < off) sh[t] += sh[t + off];
        __syncthreads();
    }
    if (t == 0) {
        float mean = (float)(sh[0] / 67108864.0);
        mean = fmaxf(mean, 1e-5f);        // clip(mean, EPS)
        float scale = 1.0f / mean;        // scale_w
        params[0] = scale;
        params[1] = 1.0f / scale;         // inv_sw
    }
}

__global__ __launch_bounds__(256) void w_quant_kernel(const float* __restrict__ w,
                                                      int8_t* __restrict__ qw,
                                                      const float* __restrict__ params) {
    const float scale = params[0];
    const int stride = gridDim.x * 256;
    const float4* w4 = (const float4*)w;
    int* q4 = (int*)qw;
    for (int g = blockIdx.x * 256 + threadIdx.x; g < 16777216; g += stride) {
        float4 v = w4[g];
        int b0 = quant_w1(v.x, scale) & 255;
        int b1 = quant_w1(v.y, scale) & 255;
        int b2 = quant_w1(v.z, scale) & 255;
        int b3 = quant_w1(v.w, scale) & 255;
        q4[g] = b0 | (b1 << 8) | (b2 << 16) | (b3 << 24);
    }
}

// ---------------- int8 GEMM: m201-faithful 256x256, BK=128B, 8 waves, 4-phase/K-tile ----
// LDS 128KB = 2 bufs x 4 regions x 16KB; regions = {A.k0, B.k0, A.k1, B.k1}, each a
// 256-row x 64B layout with the rounds-1..17-verified XOR swizzle (0 bank conflicts,
// linear global_load_lds dest). Per K-tile T (buf = T&1), 4 phases:
//   P0: ds_read a0-3.k0 + b0-3.k0 | STAGE(T+1,A.k1) | barrier | lgkm0 | 16 MFMA | barrier
//   P1: ds_read a4-7.k0           | STAGE(T+1,B.k1) | vmcnt(6) | ... | 16 MFMA | barrier
//   P2: ds_read a0-3.k1 + b0-3.k1 | STAGE(T+2,A.k0) | barrier | ... | 16 MFMA | barrier
//   P3: ds_read a4-7.k1           | STAGE(T+2,B.k0) | vmcnt(6) | ... | 16 MFMA | barrier
// Stage stream = half-tile hs p+6 at phase p (2 loads each). vmcnt(6) at P1/P3 proves
// the halves read two phases later (ledger simulated incl. prologue vm8 and tail
// vm6/vm4/vm0). Stage-into-current-buf regions are sealed by the preceding end-of-phase
// barrier (k0 regions after P1, k1 after P3 of the prior tile).
__global__ __launch_bounds__(512, 1) void gemm_i8_kernel(const int8_t* __restrict__ qx,
                                                         const int8_t* __restrict__ qw,
                                                         const float* __restrict__ inv_sx,
                                                         const float* __restrict__ params,
                                                         const float* __restrict__ bias,
                                                         float* __restrict__ y) {
    __shared__ __align__(16) int8_t lds[2][65536];
    int8_t* L = &lds[0][0];

    const int tid = threadIdx.x;      // 0..511
    const int lane = tid & 63;
    const int w = tid >> 6;           // wave 0..7
    const int wr = w >> 2;            // 0..1  (M half)
    const int wc = w & 3;             // 0..3  (N quarter)

    // XCD-aware bijective swizzle: 2048 blocks, 8 XCDs
    const int bid = blockIdx.x;
    const int swz = (bid & 7) * 256 + (bid >> 3);
    const int bn = swz & 63;          // 64 n-blocks
    const int bm = swz >> 6;          // 32 m-blocks

    const int arow0 = bm * 256;
    const int bcol0 = bn * 256;

    // staging addressing: rows r0 and r0+128, swizzled 16B chunk (verified involution)
    const int r0 = tid >> 2;                       // 0..127
    const int kc0 = (tid & 3) ^ ((r0 >> 1) & 3);
    const int8_t* gA = qx + (size_t)(arow0 + r0) * K_DIM + kc0 * 16;
    const int8_t* gB = qw + (size_t)(bcol0 + r0) * K_DIM + kc0 * 16;

#define GLD(g, l)                                                                        \
    __builtin_amdgcn_global_load_lds((const __attribute__((address_space(1))) void*)(g), \
                                     (__attribute__((address_space(3))) void*)(l), 16, 0, 0)

// stage half-tile: HALF 0=A.k0 1=B.k0 2=A.k1 3=B.k1 of K-tile tt into buf BUF
#define STAGE(tt, HALF, BUF)                                                             \
    do {                                                                                 \
        const int8_t* _s = (((HALF) & 1) ? gB : gA) + (size_t)(tt) * 128 +               \
                           (((HALF) >> 1) * 64);                                         \
        int8_t* _d = L + (BUF) * 65536 + (HALF) * 16384 + tid * 16;                      \
        GLD(_s, _d);                                                                     \
        GLD(_s + (size_t)128 * K_DIM, _d + 8192);                                        \
    } while (0)

    // fragment ds_read offsets (region-relative, verified 0-conflict pattern)
    const int ksub = lane >> 4;
    const int lrow = lane & 15;
    int aoff[8], boff[4];
#pragma unroll
    for (int i = 0; i < 8; ++i) {
        int ra = wr * 128 + i * 16 + lrow;
        aoff[i] = ra * 64 + ((ksub ^ ((ra >> 1) & 3)) << 4);
    }
#pragma unroll
    for (int j = 0; j < 4; ++j) {
        int rb = wc * 64 + j * 16 + lrow;
        boff[j] = rb * 64 + ((ksub ^ ((rb >> 1) & 3)) << 4);
    }

    v4i acc[8][4];
#pragma unroll
    for (int i = 0; i < 8; ++i)
#pragma unroll
        for (int j = 0; j < 4; ++j) acc[i][j] = (v4i){0, 0, 0, 0};

    v4i a[4], b[4];

// A regions at +0 (k0) and +32768 (k1); B regions at +16384 (k0) and +49152 (k1)
#define RDA4(BUF, KH, LO)                                                      \
    do {                                                                       \
        const int8_t* _p = L + (BUF) * 65536 + (KH) * 32768;                   \
        _Pragma("unroll") for (int _i = 0; _i < 4; ++_i)                       \
            a[_i] = *(const v4i*)(_p + aoff[(LO) + _i]);                       \
    } while (0)
#define RDB4(BUF, KH)                                                          \
    do {                                                                       \
        const int8_t* _p = L + (BUF) * 65536 + 16384 + (KH) * 32768;           \
        _Pragma("unroll") for (int _j = 0; _j < 4; ++_j)                       \
            b[_j] = *(const v4i*)(_p + boff[_j]);                              \
    } while (0)

#define MF16(MH)                                                               \
    do {                                                                       \
        __builtin_amdgcn_s_setprio(1);                                         \
        _Pragma("unroll") for (int _i = 0; _i < 4; ++_i)                       \
            _Pragma("unroll") for (int _j = 0; _j < 4; ++_j)                   \
                acc[(MH) * 4 + _i][_j] = __builtin_amdgcn_mfma_i32_16x16x64_i8(\
                    a[_i], b[_j], acc[(MH) * 4 + _i][_j], 0, 0, 0);            \
        __builtin_amdgcn_s_setprio(0);                                         \
    } while (0)

#define BARR()                                                                 \
    do {                                                                       \
        __builtin_amdgcn_s_barrier();                                          \
        __builtin_amdgcn_sched_barrier(0);                                     \
    } while (0)
#define LGKM0()                                                                \
    do {                                                                       \
        asm volatile("s_waitcnt lgkmcnt(0)" ::: "memory");                     \
        __builtin_amdgcn_sched_barrier(0);                                     \
    } while (0)
#define VM(NSTR) asm volatile("s_waitcnt vmcnt(" NSTR ")" ::: "memory")

    // prologue: hs0..5 = tile0 halves 0-3 (buf0) + tile1 halves 0-1 (buf1); 12 loads
    STAGE(0, 0, 0); STAGE(0, 1, 0); STAGE(0, 2, 0); STAGE(0, 3, 0);
    STAGE(1, 0, 1); STAGE(1, 1, 1);
    VM("8");                          // proves hs0,1 = tile0 {A.k0, B.k0}
    BARR();

    // main loop: 15 iters x 2 tiles (tiles 0..29); stages through hs125 (= tile31.B.k0)
#pragma unroll 1
    for (int j = 0; j < 15; ++j) {
        const int T = 2 * j;
        // tile T (buf0)
        RDA4(0, 0, 0); RDB4(0, 0); STAGE(T + 1, 2, 1);            BARR(); LGKM0(); MF16(0); BARR();
        RDA4(0, 0, 4);             STAGE(T + 1, 3, 1); VM("6");   BARR(); LGKM0(); MF16(1); BARR();
        RDA4(0, 1, 0); RDB4(0, 1); STAGE(T + 2, 0, 0);            BARR(); LGKM0(); MF16(0); BARR();
        RDA4(0, 1, 4);             STAGE(T + 2, 1, 0); VM("6");   BARR(); LGKM0(); MF16(1); BARR();
        // tile T+1 (buf1)
        RDA4(1, 0, 0); RDB4(1, 0); STAGE(T + 2, 2, 0);            BARR(); LGKM0(); MF16(0); BARR();
        RDA4(1, 0, 4);             STAGE(T + 2, 3, 0); VM("6");   BARR(); LGKM0(); MF16(1); BARR();
        RDA4(1, 1, 0); RDB4(1, 1); STAGE(T + 3, 0, 1);            BARR(); LGKM0(); MF16(0); BARR();
        RDA4(1, 1, 4);             STAGE(T + 3, 1, 1); VM("6");   BARR(); LGKM0(); MF16(1); BARR();
    }
    // tail: tile 30 (buf0) — stage the last two halves (tile31 k1)
    RDA4(0, 0, 0); RDB4(0, 0); STAGE(31, 2, 1);                   BARR(); LGKM0(); MF16(0); BARR();
    RDA4(0, 0, 4);             STAGE(31, 3, 1); VM("6");          BARR(); LGKM0(); MF16(1); BARR();
    RDA4(0, 1, 0); RDB4(0, 1);                                    BARR(); LGKM0(); MF16(0); BARR();
    RDA4(0, 1, 4);                              VM("4");          BARR(); LGKM0(); MF16(1); BARR();
    // tile 31 (buf1)
    RDA4(1, 0, 0); RDB4(1, 0);                                    BARR(); LGKM0(); MF16(0); BARR();
    RDA4(1, 0, 4);                              VM("0");          BARR(); LGKM0(); MF16(1); BARR();
    RDA4(1, 1, 0); RDB4(1, 1);                                    BARR(); LGKM0(); MF16(0); BARR();
    RDA4(1, 1, 4);                                                        LGKM0(); MF16(1);

    // epilogue: y = acc * inv_sx[row] * inv_sw + bias[col]  (verified 16x16 C/D layout)
    const float invsw = params[1];
    const int rl = (lane >> 4) * 4;
#pragma unroll
    for (int i = 0; i < 8; ++i) {
        const int grow_base = arow0 + wr * 128 + i * 16 + rl;
        float isx[4];
#pragma unroll
        for (int r = 0; r < 4; ++r) isx[r] = inv_sx[grow_base + r] * invsw;
#pragma unroll
        for (int j = 0; j < 4; ++j) {
            const int gcol = bcol0 + wc * 64 + j * 16 + lrow;
            const float bb = bias[gcol];
#pragma unroll
            for (int r = 0; r < 4; ++r) {
                y[(size_t)(grow_base + r) * N_COLS + gcol] =
                    (float)acc[i][j][r] * isx[r] + bb;
            }
        }
    }
#undef GLD
#undef STAGE
#undef RDA4
#undef RDB4
#undef MF16
#undef BARR
#undef LGKM0
#undef VM
}

// ---------------- launch ----------------
extern "C" void kernel_launch(void* const* d_in, const int* in_sizes, int n_in,
                              void* d_out, int out_size, void* d_ws, size_t ws_size,
                              hipStream_t stream) {
    const float* x    = (const float*)d_in[0];
    const float* wt   = (const float*)d_in[1];
    const float* bias = (const float*)d_in[2];
    float* y = (float*)d_out;

    if (ws_size < WS_NEED) return;

    char* ws = (char*)d_ws;
    float* partials = (float*)(ws + WS_PARTIALS);
    float* params   = (float*)(ws + WS_PARAMS);
    float* inv_sx   = (float*)(ws + WS_INVSX);
    int8_t* qx = (int8_t*)(ws + WS_QX);
    int8_t* qw = (int8_t*)(ws + WS_QW);

    hipLaunchKernelGGL(fused_quant_kernel, dim3(10240), dim3(256), 0, stream,
                       x, qx, inv_sx, wt, partials);
    hipLaunchKernelGGL(wfinal_kernel,      dim3(1),    dim3(256), 0, stream, partials, params);
    hipLaunchKernelGGL(w_quant_kernel,     dim3(4096), dim3(256), 0, stream, wt, qw, params);
    hipLaunchKernelGGL(gemm_i8_kernel,     dim3(2048), dim3(512), 0, stream,
                       qx, qw, inv_sx, params, bias, y);
}

// Round 19
// 707.410 us; speedup vs baseline: 1.0607x; 1.0113x over previous
//
#include <hip/hip_runtime.h>
#include <stdint.h>

// BitNet b1.58 column-parallel linear:
//   y[m,n] = (sum_k qx[m,k]*qw[n,k]) * inv_sx[m] * inv_sw + bias[n]
// M=8192 (B*S), N=16384 (D_OUT), K=4096 (D_IN)
//
// FINAL (R15 restore): R9 GEMM (best of 8 structural families tested over 18 rounds:
// 574us, MfmaUtil 43.6%, 0 bank conflicts) + fused quant kernels.
// Structural limit analysis: per CU/K-step LDS traffic (96KB frag reads + 48KB staging
// writes) >= MFMA pipe time at every register-feasible geometry; the intensity fix
// (128x128/wave) needs >256 unified regs/wave => 1 wave/SIMD => latency-bound (R7: 33%).

#define M_ROWS 8192
#define N_COLS 16384
#define K_DIM  4096
#define NT     (K_DIM / 64)   // 64 K-steps of 64 bytes

typedef int v4i __attribute__((ext_vector_type(4)));

// ---------------- workspace layout ----------------
#define WS_PARTIALS 0
#define WS_PARAMS   8192
#define WS_INVSX    8448
#define WS_QX       41216
#define WS_QW       (41216 + 33554432)
#define WS_NEED     ((size_t)WS_QW + 67108864)

// ---------------- fused: activation quant (blocks 0..8191) + weight abs-sum partials
// (blocks 8192..10239). Independent memory-bound passes overlapped in one launch.
__device__ __forceinline__ int quant_act1(float v, float s) {
    float q = rintf(v * s);               // round-half-even, matches jnp.round
    q = fminf(127.0f, fmaxf(-128.0f, q));
    return (int)q;
}

__global__ __launch_bounds__(256) void fused_quant_kernel(const float* __restrict__ x,
                                                          int8_t* __restrict__ qx,
                                                          float* __restrict__ inv_sx,
                                                          const float* __restrict__ w,
                                                          float* __restrict__ partials) {
    const int t = threadIdx.x;
    if (blockIdx.x < 8192) {
        // ---- activation quant: per-row int8 absmax ----
        const int row = blockIdx.x;
        const float4* xr = (const float4*)(x + (size_t)row * K_DIM);

        float4 v[4];
        float m = 0.0f;
#pragma unroll
        for (int i = 0; i < 4; ++i) {
            v[i] = xr[t + 256 * i];
            m = fmaxf(m, fmaxf(fmaxf(fabsf(v[i].x), fabsf(v[i].y)),
                               fmaxf(fabsf(v[i].z), fabsf(v[i].w))));
        }
#pragma unroll
        for (int off = 32; off > 0; off >>= 1) m = fmaxf(m, __shfl_xor(m, off));
        __shared__ float wm[4];
        if ((t & 63) == 0) wm[t >> 6] = m;
        __syncthreads();
        m = fmaxf(fmaxf(wm[0], wm[1]), fmaxf(wm[2], wm[3]));
        m = fmaxf(m, 1e-5f);              // clip(max, EPS)
        const float scale = 127.0f / m;
        if (t == 0) inv_sx[row] = 1.0f / scale;

        int* qr = (int*)(qx + (size_t)row * K_DIM);
#pragma unroll
        for (int i = 0; i < 4; ++i) {
            int b0 = quant_act1(v[i].x, scale) & 255;
            int b1 = quant_act1(v[i].y, scale) & 255;
            int b2 = quant_act1(v[i].z, scale) & 255;
            int b3 = quant_act1(v[i].w, scale) & 255;
            qr[t + 256 * i] = b0 | (b1 << 8) | (b2 << 16) | (b3 << 24);
        }
    } else {
        // ---- weight abs-sum partial (deterministic) ----
        const int pb = blockIdx.x - 8192;             // 0..2047
        const size_t base = (size_t)pb * 8192;        // float4 units
        const float4* w4 = (const float4*)w;
        float s = 0.0f;
#pragma unroll 8
        for (int i = 0; i < 32; ++i) {
            float4 v = w4[base + (size_t)i * 256 + t];
            s += fabsf(v.x) + fabsf(v.y) + fabsf(v.z) + fabsf(v.w);
        }
#pragma unroll
        for (int off = 32; off > 0; off >>= 1) s += __shfl_xor(s, off);
        __shared__ float wp[4];
        if ((t & 63) == 0) wp[t >> 6] = s;
        __syncthreads();
        if (t == 0) partials[pb] = (wp[0] + wp[1]) + (wp[2] + wp[3]);
    }
}

__global__ __launch_bounds__(256) void wfinal_kernel(const float* __restrict__ partials,
                                                     float* __restrict__ params) {
    __shared__ double sh[256];
    const int t = threadIdx.x;
    double s = 0.0;
    for (int i = t; i < 2048; i += 256) s += (double)partials[i];
    sh[t] = s;
    __syncthreads();
    for (int off = 128; off > 0; off >>= 1) {
        if (t < off) sh[t] += sh[t + off];
        __syncthreads();
    }
    if (t == 0) {
        float mean = (float)(sh[0] / 67108864.0);
        mean = fmaxf(mean, 1e-5f);        // clip(mean, EPS)
        float scale = 1.0f / mean;        // scale_w
        params[0] = scale;
        params[1] = 1.0f / scale;         // inv_sw
    }
}

// ---------------- weight quant: per-tensor ternary ----------------
__device__ __forceinline__ int quant_w1(float v, float s) {
    float q = rintf(v * s);
    q = fminf(1.0f, fmaxf(-1.0f, q));
    return (int)q;
}

__global__ __launch_bounds__(256) void w_quant_kernel(const float* __restrict__ w,
                                                      int8_t* __restrict__ qw,
                                                      const float* __restrict__ params) {
    const float scale = params[0];
    const int stride = gridDim.x * 256;
    const float4* w4 = (const float4*)w;
    int* q4 = (int*)qw;
    for (int g = blockIdx.x * 256 + threadIdx.x; g < 16777216; g += stride) {
        float4 v = w4[g];
        int b0 = quant_w1(v.x, scale) & 255;
        int b1 = quant_w1(v.y, scale) & 255;
        int b2 = quant_w1(v.z, scale) & 255;
        int b3 = quant_w1(v.w, scale) & 255;
        q4[g] = b0 | (b1 << 8) | (b2 << 16) | (b3 << 24);
    }
}

// ---------------- int8 GEMM: 256x128 tile, 4 waves, 3-slot ring, 2 BLOCKS/CU ----
// (R9 — best verified: 574us, MfmaUtil 43.6%, 0 bank conflicts.)
// m114 mechanism: two independent co-resident blocks per CU (LDS 72KB x 2 <= 160KB,
// regs <= 256/wave incl AGPR via launch_bounds(256,2)) provide MFMA<->LDS overlap.
// 4 waves (2M x 2N), per-wave 128x64, mfma_i32_16x16x64_i8 (verified layout).
// 3-slot ring (slot = t%3), stage-2-ahead, 6 GLD/thread/step (4 A + 2 B).
// Per step t: { 12 ds_read slot t%3 | GLD6(t+2 -> (t+2)%3) | 32 MFMA |
//              vmcnt(6) [proves K(t+1)] | s_barrier [publishes slot (t+1)%3] }.
// Slot-overwrite safety: GLD(t+2) targets slot (t-1)%3 whose reads drained before the
// end-of-(t-1) barrier (MFMA reg deps force lgkm completion pre-barrier).
// 16B-chunk XOR swizzle on global source + ds_read addr (rounds 1-18: 0 conflicts).
__global__ __launch_bounds__(256, 2) void gemm_i8_kernel(const int8_t* __restrict__ qx,
                                                         const int8_t* __restrict__ qw,
                                                         const float* __restrict__ inv_sx,
                                                         const float* __restrict__ params,
                                                         const float* __restrict__ bias,
                                                         float* __restrict__ y) {
    __shared__ __align__(16) int8_t lds[3][24576];   // per slot: A[256][64] + B[128][64]
    int8_t* L = &lds[0][0];

    const int tid = threadIdx.x;
    const int lane = tid & 63;
    const int w = tid >> 6;           // wave 0..3
    const int wr = w >> 1;            // 0..1  (M half)
    const int wc = w & 1;             // 0..1  (N half)
    const int wbase = w * 1024;       // wave-uniform LDS staging base

    // XCD-aware bijective swizzle: 4096 blocks, 8 XCDs
    const int bid = blockIdx.x;
    const int swz = (bid & 7) * 512 + (bid >> 3);
    const int bn = swz & 127;         // 128 n-blocks (fast: consecutive share A-panel)
    const int bm = swz >> 7;          // 32 m-blocks

    const size_t arow0 = (size_t)bm * 256;
    const size_t bcol0 = (size_t)bn * 128;

    // staging: A 1024 chunks of 16B (4/thread, row stride 64), B 512 chunks (2/thread)
    const int r0 = tid >> 2;                       // 0..63
    const int kc0 = (tid & 3) ^ ((r0 >> 1) & 3);   // swizzled k-slot (involution)
    const int8_t* gA = qx + (arow0 + r0) * K_DIM + kc0 * 16;
    const int8_t* gB = qw + (bcol0 + r0) * K_DIM + kc0 * 16;

#define GLD(g, l)                                                                        \
    __builtin_amdgcn_global_load_lds((const __attribute__((address_space(1))) void*)(g), \
                                     (__attribute__((address_space(3))) void*)(l), 16, 0, 0)

// stage K-step ks into slot S: 4 A chunks + 2 B chunks per thread
#define GLD6(ks, S)                                                                      \
    do {                                                                                 \
        const size_t _o = (size_t)(ks) * 64;                                             \
        _Pragma("unroll") for (int _g = 0; _g < 4; ++_g)                                 \
            GLD(gA + _o + (size_t)_g * (64 * K_DIM),                                     \
                L + (S) * 24576 + _g * 4096 + wbase);                                    \
        _Pragma("unroll") for (int _h = 0; _h < 2; ++_h)                                 \
            GLD(gB + _o + (size_t)_h * (64 * K_DIM),                                     \
                L + (S) * 24576 + 16384 + _h * 4096 + wbase);                            \
    } while (0)

    // fragment ds_read offsets (within one 24KB slot) — verified 16x16x64 layout
    const int ksub = lane >> 4;       // 16B k-chunk 0..3
    const int lrow = lane & 15;
    int aoff[8], boff[4];
#pragma unroll
    for (int i = 0; i < 8; ++i) {
        int ra = wr * 128 + i * 16 + lrow;
        aoff[i] = ra * 64 + ((ksub ^ ((ra >> 1) & 3)) << 4);
    }
#pragma unroll
    for (int j = 0; j < 4; ++j) {
        int rb = wc * 64 + j * 16 + lrow;
        boff[j] = 16384 + rb * 64 + ((ksub ^ ((rb >> 1) & 3)) << 4);
    }

    v4i acc[8][4];
#pragma unroll
    for (int i = 0; i < 8; ++i)
#pragma unroll
        for (int j = 0; j < 4; ++j) acc[i][j] = (v4i){0, 0, 0, 0};

#define BARR()                                                                 \
    do {                                                                       \
        __builtin_amdgcn_s_barrier();                                          \
        __builtin_amdgcn_sched_barrier(0);                                     \
    } while (0)
#define VM(NSTR) asm volatile("s_waitcnt vmcnt(" NSTR ")" ::: "memory")

// One K-step: read 12 frags from slot CS, stage FKS (if STG), 32 MFMA, wait, barrier.
#define STEP(CS, FKS, FSL, STG, VMSTMT, DOBAR)                                 \
    do {                                                                       \
        const int8_t* _p = L + (CS) * 24576;                                   \
        v4i a[8], b[4];                                                        \
        _Pragma("unroll") for (int _i = 0; _i < 8; ++_i)                       \
            a[_i] = *(const v4i*)(_p + aoff[_i]);                              \
        _Pragma("unroll") for (int _j = 0; _j < 4; ++_j)                       \
            b[_j] = *(const v4i*)(_p + boff[_j]);                              \
        if (STG) GLD6(FKS, FSL);                                               \
        __builtin_amdgcn_s_setprio(1);                                         \
        _Pragma("unroll") for (int _i = 0; _i < 8; ++_i)                       \
            _Pragma("unroll") for (int _j = 0; _j < 4; ++_j)                   \
                acc[_i][_j] = __builtin_amdgcn_mfma_i32_16x16x64_i8(           \
                    a[_i], b[_j], acc[_i][_j], 0, 0, 0);                       \
        __builtin_amdgcn_s_setprio(0);                                         \
        VMSTMT;                                                                \
        if (DOBAR) BARR();                                                     \
    } while (0)

    // prologue: stage K0->s0, K1->s1; vmcnt(6) proves K0; barrier publishes s0
    GLD6(0, 0);
    GLD6(1, 1);
    VM("6");
    BARR();

    // main loop: j=0..19, K-steps 3j..3j+2 (t=0..59), staging t+2 (slots 2,0,1)
#pragma unroll 1
    for (int j = 0; j < 20; ++j) {
        const int tb = 3 * j;
        STEP(0, tb + 2, 2, 1, VM("6"), 1);   // t=3j: proves K(t+1)
        STEP(1, tb + 3, 0, 1, VM("6"), 1);
        STEP(2, tb + 4, 1, 1, VM("6"), 1);
    }
    // tail: t=60..63 (slots 0,1,2,0); K62 staged at t=60, K63 at t=61
    STEP(0, 62, 2, 1, VM("6"), 1);     // t=60: proves K61
    STEP(1, 63, 0, 1, VM("6"), 1);     // t=61: proves K62
    STEP(2, 0, 0, 0, VM("0"), 1);      // t=62: proves K63
    STEP(0, 0, 0, 0, (void)0, 0);      // t=63

    // epilogue: y = acc * inv_sx[row] * inv_sw + bias[col]  (verified 16x16 C/D layout)
    const float invsw = params[1];
    const int rl = (lane >> 4) * 4;
#pragma unroll
    for (int i = 0; i < 8; ++i) {
        const int grow_base = (int)arow0 + wr * 128 + i * 16 + rl;
        float isx[4];
#pragma unroll
        for (int r = 0; r < 4; ++r) isx[r] = inv_sx[grow_base + r] * invsw;
#pragma unroll
        for (int j = 0; j < 4; ++j) {
            const int gcol = (int)bcol0 + wc * 64 + j * 16 + lrow;
            const float bb = bias[gcol];
#pragma unroll
            for (int r = 0; r < 4; ++r) {
                y[(size_t)(grow_base + r) * N_COLS + gcol] =
                    (float)acc[i][j][r] * isx[r] + bb;
            }
        }
    }
#undef GLD
#undef GLD6
#undef BARR
#undef VM
#undef STEP
}

// ---------------- launch ----------------
extern "C" void kernel_launch(void* const* d_in, const int* in_sizes, int n_in,
                              void* d_out, int out_size, void* d_ws, size_t ws_size,
                              hipStream_t stream) {
    const float* x    = (const float*)d_in[0];
    const float* wt   = (const float*)d_in[1];
    const float* bias = (const float*)d_in[2];
    float* y = (float*)d_out;

    if (ws_size < WS_NEED) return;

    char* ws = (char*)d_ws;
    float* partials = (float*)(ws + WS_PARTIALS);
    float* params   = (float*)(ws + WS_PARAMS);
    float* inv_sx   = (float*)(ws + WS_INVSX);
    int8_t* qx = (int8_t*)(ws + WS_QX);
    int8_t* qw = (int8_t*)(ws + WS_QW);

    hipLaunchKernelGGL(fused_quant_kernel, dim3(10240), dim3(256), 0, stream,
                       x, qx, inv_sx, wt, partials);
    hipLaunchKernelGGL(wfinal_kernel,      dim3(1),    dim3(256), 0, stream, partials, params);
    hipLaunchKernelGGL(w_quant_kernel,     dim3(4096), dim3(256), 0, stream, wt, qw, params);
    hipLaunchKernelGGL(gemm_i8_kernel,     dim3(4096), dim3(256), 0, stream,
                       qx, qw, inv_sx, params, bias, y);
}